// Round 5
// baseline (266.629 us; speedup 1.0000x reference)
//
#include <hip/hip_runtime.h>

#define N_NODES 100000
#define N_EDGES 50000
#define N_KEYS  150000   // node keys [0,100000) then edge keys [100000,150000)
#define M_INC   1600000
#define D_HID   64

#define SUBR    32       // incidence subranges
#define SUBLEN  50000    // M_INC / SUBR
#define KPART   65536    // keys per LDS partition (u8 counts packed in 64KB LDS)
#define PN      2        // ceil(100000/65536)
#define PE      1        // ceil(50000/65536)

#define N_TILES_N 25   // ceil(100000/4096)
#define N_TILES_E 13   // ceil(50000/4096)

#define NBKT    128      // slot-buckets per target
#define BKT_SZ  12500    // slots per bucket (128*12500 == M_INC exactly)

typedef float v2f __attribute__((ext_vector_type(2)));

// ---- workspace layout (byte offsets, lifetime-overlapped) ----
// rank_n u8 @0 (1.6MB), rank_e u8 @1600000 (1.6MB)  -- dead after binA
// ef fp8 [3.2MB] @0                                 -- written by stage1 (post-binA)
// noff @3200000, eoff @3600016, cur @3800032, scan @3801056
// node_csr u16 @3801600 (3.2MB), edge_csr i32 @7001600 (6.4MB)
//   tot int [600KB] overlaps node_csr (dead after scan_write, csr written in binB)
// rb u16 @13401600 (9.6MB)                          -- dead after binA
//   xh fp8 [6.4MB] overlays rb (written by cvt, after binA)
// bin_n u32 @23001600 (6.4MB), bin_e u32 @29401600 (6.4MB)
//   cnt_g u16 [9.6MB] overlaps bins (dead after replprefix; bins written in binA)
// peak: 35,801,600 B = 34.2 MiB

__device__ __forceinline__ unsigned enc_fp8x4(float a, float b, float c, float d) {
    unsigned r = 0;
    r = __builtin_amdgcn_cvt_pk_fp8_f32(a, b, r, false);
    r = __builtin_amdgcn_cvt_pk_fp8_f32(c, d, r, true);
    return r;
}

// Counting without global atomics: block (p,s) filters subrange s for keys in
// partition p. u8 counts packed 4-per-u32 in LDS (64KB = 65536 keys) -> only
// PN=2 node + PE=1 edge partitions. rank = old byte from packed atomicAdd.
__global__ __launch_bounds__(1024) void count_kernel(
        const int* __restrict__ node_idx, const int* __restrict__ edge_idx,
        unsigned char* __restrict__ rank_n, unsigned char* __restrict__ rank_e,
        unsigned short* __restrict__ cnt_g) {
    __shared__ unsigned int h[KPART / 4];
    int bid = blockIdx.x;
    const int* idx; unsigned char* rk; int p, s, klim, goff;
    if (bid < PN * SUBR) {
        p = bid / SUBR; s = bid % SUBR;
        idx = node_idx; rk = rank_n; klim = N_NODES; goff = 0;
    } else {
        int b2 = bid - PN * SUBR;
        p = b2 / SUBR; s = b2 % SUBR;
        idx = edge_idx; rk = rank_e; klim = N_EDGES; goff = N_NODES;
    }
    int kbase = p * KPART;
    int t = threadIdx.x;
    for (int i = t; i < KPART / 4; i += 1024) h[i] = 0;
    __syncthreads();
    int mbase = s * SUBLEN;
    const int4* src4 = (const int4*)(idx + mbase);
    for (int i = t; i < SUBLEN / 4; i += 1024) {
        int4 v = src4[i];
        int m0 = mbase + i * 4;
        int k;
        k = v.x - kbase;
        if ((unsigned)k < KPART) {
            unsigned sh = 8u * (k & 3);
            unsigned old = atomicAdd(&h[k >> 2], 1u << sh);
            rk[m0 + 0] = (unsigned char)(old >> sh);
        }
        k = v.y - kbase;
        if ((unsigned)k < KPART) {
            unsigned sh = 8u * (k & 3);
            unsigned old = atomicAdd(&h[k >> 2], 1u << sh);
            rk[m0 + 1] = (unsigned char)(old >> sh);
        }
        k = v.z - kbase;
        if ((unsigned)k < KPART) {
            unsigned sh = 8u * (k & 3);
            unsigned old = atomicAdd(&h[k >> 2], 1u << sh);
            rk[m0 + 2] = (unsigned char)(old >> sh);
        }
        k = v.w - kbase;
        if ((unsigned)k < KPART) {
            unsigned sh = 8u * (k & 3);
            unsigned old = atomicAdd(&h[k >> 2], 1u << sh);
            rk[m0 + 3] = (unsigned char)(old >> sh);
        }
    }
    __syncthreads();
    for (int i = t; i < KPART; i += 1024) {
        int key = kbase + i;
        if (key < klim)
            cnt_g[s * N_KEYS + goff + key] =
                (unsigned short)((h[i >> 2] >> (8u * (i & 3))) & 0xFFu);
    }
}

// Per-key prefix over the 32 subrange counts -> rb[s][key] (u16); totals -> tot[key].
__global__ void replprefix_kernel(const unsigned short* __restrict__ cnt_g,
                                  unsigned short* __restrict__ rb, int* __restrict__ tot) {
    int key = blockIdx.x * 256 + threadIdx.x;
    if (key < N_KEYS) {
        int base = 0;
#pragma unroll
        for (int k = 0; k < SUBR; k++) {
            rb[k * N_KEYS + key] = (unsigned short)base;
            base += (int)cnt_g[k * N_KEYS + key];
        }
        tot[key] = base;
    }
}

// Scan stage 1: per-tile (4096 elements) sums over the contiguous totals array.
__global__ void scan_partial_kernel(const int* __restrict__ cnt,
                                    int* __restrict__ pn, int* __restrict__ pe) {
    __shared__ int lds[16];
    int b = blockIdx.x;
    const int* src; int nElem; int tile; int* dst;
    if (b < N_TILES_N) { src = cnt;            nElem = N_NODES; tile = b;             dst = pn; }
    else               { src = cnt + N_NODES;  nElem = N_EDGES; tile = b - N_TILES_N; dst = pe; }
    int t = threadIdx.x;
    int i4 = tile * 1024 + t;
    int sum = 0;
    if (i4 * 4 < nElem) {
        int4 v = ((const int4*)src)[i4];
        sum = v.x + v.y + v.z + v.w;
    }
    for (int off = 1; off < 64; off <<= 1) sum += __shfl_xor(sum, off, 64);
    if ((t & 63) == 0) lds[t >> 6] = sum;
    __syncthreads();
    if (t < 16) {
        int s = lds[t];
        for (int off = 1; off < 16; off <<= 1) s += __shfl_xor(s, off, 64);
        if (t == 0) dst[tile] = s;
    }
}

// Scan stage 2: exclusive scan of tile sums; sentinel offsets; binA cursor init.
__global__ void scan_base_kernel(const int* __restrict__ pn, const int* __restrict__ pe,
                                 int* __restrict__ bn, int* __restrict__ be,
                                 int* __restrict__ noff, int* __restrict__ eoff,
                                 int* __restrict__ cur) {
    int t = threadIdx.x;
    int lane = t & 63;
    if (t < 64) {
        int v = (lane < N_TILES_N) ? pn[lane] : 0;
        int incl = v;
        for (int d = 1; d < 64; d <<= 1) { int u = __shfl_up(incl, d, 64); if (lane >= d) incl += u; }
        if (lane < N_TILES_N) bn[lane] = incl - v;
        if (lane == N_TILES_N - 1) noff[N_NODES] = incl;
    } else if (t < 128) {
        int v = (lane < N_TILES_E) ? pe[lane] : 0;
        int incl = v;
        for (int d = 1; d < 64; d <<= 1) { int u = __shfl_up(incl, d, 64); if (lane >= d) incl += u; }
        if (lane < N_TILES_E) be[lane] = incl - v;
        if (lane == N_TILES_E - 1) eoff[N_EDGES] = incl;
    } else {
        int i = t - 128;                 // 0..127: per-bucket bin cursors
        cur[i] = i * BKT_SZ;             // node buckets (bin_n-relative)
        cur[i + NBKT] = i * BKT_SZ;      // edge buckets (bin_e-relative)
    }
}

// Scan stage 3: block-level exclusive scan of each tile + tile base, int4 I/O.
__global__ void scan_write_kernel(const int* __restrict__ cnt,
                                  const int* __restrict__ bn, const int* __restrict__ be,
                                  int* __restrict__ noff, int* __restrict__ eoff) {
    __shared__ int wsum[16];
    int b = blockIdx.x;
    const int* src; int* dst; int nElem; int tile; int tbase;
    if (b < N_TILES_N) { src = cnt;           dst = noff; nElem = N_NODES; tile = b;             tbase = bn[tile]; }
    else               { src = cnt + N_NODES; dst = eoff; nElem = N_EDGES; tile = b - N_TILES_N; tbase = be[tile]; }
    int t = threadIdx.x;
    int lane = t & 63, w = t >> 6;
    int i4 = tile * 1024 + t;
    int4 c = make_int4(0, 0, 0, 0);
    bool valid = (i4 * 4 < nElem);
    if (valid) c = ((const int4*)src)[i4];
    int tsum = c.x + c.y + c.z + c.w;
    int incl = tsum;
    for (int d = 1; d < 64; d <<= 1) { int u = __shfl_up(incl, d, 64); if (lane >= d) incl += u; }
    if (lane == 63) wsum[w] = incl;
    __syncthreads();
    if (t < 16) {
        int v = wsum[t];
        int wi = v;
        for (int d = 1; d < 16; d <<= 1) { int u = __shfl_up(wi, d, 64); if (t >= d) wi += u; }
        wsum[t] = wi - v;
    }
    __syncthreads();
    int ex = tbase + wsum[w] + incl - tsum;
    if (valid) {
        int4 o;
        o.x = ex; o.y = ex + c.x; o.z = o.y + c.y; o.w = o.z + c.z;
        ((int4*)dst)[i4] = o;
    }
}

// binA: pass 1 of the two-pass fill. Same gathers as the old fill (idx, u8
// ranks, rb, noff/eoff) -> slot = off[key]+rb+rank, but instead of a random
// 12.8MB-window scatter (96MB write amp), entries are packed to u32
// (rel-slot<<17 | val; slots are a permutation of [0,1.6M) so bucket
// b=slot/12500 has EXACTLY 12500 entries) and placed cursor-contiguously per
// bucket: LDS per-bucket histogram -> one global atomicAdd per block-bucket.
__global__ __launch_bounds__(512) void binA_kernel(
        const int* __restrict__ node_idx, const int* __restrict__ edge_idx,
        const unsigned char* __restrict__ rank_n, const unsigned char* __restrict__ rank_e,
        const unsigned short* __restrict__ rb,
        const int* __restrict__ noff, const int* __restrict__ eoff,
        int* __restrict__ cur,
        unsigned int* __restrict__ bin_n, unsigned int* __restrict__ bin_e) {
    __shared__ unsigned int hist[2 * NBKT];
    __shared__ unsigned int gbase[2 * NBKT];
    int t = threadIdx.x;
    if (t < 2 * NBKT) hist[t] = 0;
    __syncthreads();
    unsigned pk[16];   // packed entries: (rel-slot<<17)|val
    unsigned mt[16];   // meta: (bucket<<13)|lrank ; 0xFFFFFFFF = invalid
    int cbase = blockIdx.x * 1024;   // int4-batches per block
#pragma unroll
    for (int j = 0; j < 2; j++) {
        int q = cbase + t * 2 + j;
        bool valid = q < M_INC / 4;
        int4 nv = make_int4(0, 0, 0, 0), ev = make_int4(0, 0, 0, 0);
        uchar4 rn = make_uchar4(0, 0, 0, 0), re = make_uchar4(0, 0, 0, 0);
        const unsigned short* rbs = rb;
        if (valid) {
            nv = ((const int4*)node_idx)[q];
            ev = ((const int4*)edge_idx)[q];
            rn = ((const uchar4*)rank_n)[q];
            re = ((const uchar4*)rank_e)[q];
            rbs = rb + ((q * 4) / SUBLEN) * N_KEYS;   // batch never straddles subranges
        }
        int ns[4] = {nv.x, nv.y, nv.z, nv.w};
        int es[4] = {ev.x, ev.y, ev.z, ev.w};
        int rns[4] = {rn.x, rn.y, rn.z, rn.w};
        int res[4] = {re.x, re.y, re.z, re.w};
#pragma unroll
        for (int k = 0; k < 4; k++) {
            int idxn = j * 8 + k, idxe = j * 8 + 4 + k;
            if (valid) {
                int n = ns[k], e = es[k];
                int slot = noff[n] + (int)rbs[n] + rns[k];
                int b = slot / BKT_SZ;
                unsigned lr = atomicAdd(&hist[b], 1u);
                pk[idxn] = ((unsigned)(slot - b * BKT_SZ) << 17) | (unsigned)e;
                mt[idxn] = ((unsigned)b << 13) | lr;
                slot = eoff[e] + (int)rbs[N_NODES + e] + res[k];
                b = slot / BKT_SZ;
                lr = atomicAdd(&hist[NBKT + b], 1u);
                pk[idxe] = ((unsigned)(slot - b * BKT_SZ) << 17) | (unsigned)n;
                mt[idxe] = ((unsigned)(NBKT + b) << 13) | lr;
            } else {
                mt[idxn] = 0xFFFFFFFFu;
                mt[idxe] = 0xFFFFFFFFu;
            }
        }
    }
    __syncthreads();
    if (t < 2 * NBKT) gbase[t] = (unsigned)atomicAdd(&cur[t], (int)hist[t]);
    __syncthreads();
#pragma unroll
    for (int i = 0; i < 16; i++) {
        if (mt[i] != 0xFFFFFFFFu) {
            unsigned b = mt[i] >> 13;
            unsigned pos = gbase[b] + (mt[i] & 0x1FFFu);
            if (b < NBKT) bin_n[pos] = pk[i];
            else          bin_e[pos] = pk[i];
        }
    }
}

// binB: pass 2. One block per bucket: sequential 50KB bin read, scatter into
// the bucket's 25-50KB CSR window (L2-resident -> lines fill before eviction,
// clean full-line write-back). node_csr is u16 (edge ids < 50000).
__global__ __launch_bounds__(512) void binB_kernel(
        const unsigned int* __restrict__ bin_n, const unsigned int* __restrict__ bin_e,
        unsigned short* __restrict__ node_csr, int* __restrict__ edge_csr) {
    int b = blockIdx.x;
    if (b < NBKT) {
        int base = b * BKT_SZ;
        for (int i = threadIdx.x; i < BKT_SZ; i += 512) {
            unsigned p = bin_n[base + i];
            node_csr[base + (int)(p >> 17)] = (unsigned short)(p & 0x1FFFFu);
        }
    } else {
        int base = (b - NBKT) * BKT_SZ;
        for (int i = threadIdx.x; i < BKT_SZ; i += 512) {
            unsigned p = bin_e[base + i];
            edge_csr[base + (int)(p >> 17)] = (int)(p & 0x1FFFFu);
        }
    }
}

// Convert x (fp32) -> xh (fp8 e4m3, HW RNE). 8 elements / thread, coalesced.
__global__ void cvt_kernel(const float* __restrict__ x, uint2* __restrict__ xh) {
    int i = blockIdx.x * 256 + threadIdx.x;           // 8-element group
    if (i < (N_NODES * D_HID) / 8) {
        const float4* x4 = (const float4*)x;
        float4 a = x4[i * 2], b = x4[i * 2 + 1];
        uint2 o;
        o.x = enc_fp8x4(a.x, a.y, a.z, a.w);
        o.y = enc_fp8x4(b.x, b.y, b.z, b.w);
        xh[i] = o;
    }
}

// Stage 1: one wave per edge; 8 member-groups x 8 lanes, 8B (8 fp8) per lane.
// Output ef in fp8 (row = 64B, ef total 3.2MB).
__global__ void stage1_kernel(const int* __restrict__ eoff, const int* __restrict__ ecsr,
                              const uint2* __restrict__ xh, uint2* __restrict__ ef) {
    int wid = (blockIdx.x * 256 + threadIdx.x) >> 6;
    if (wid >= N_EDGES) return;
    int lane = threadIdx.x & 63;
    int group = lane >> 3;
    int gl = lane & 7;
    int s = eoff[wid], t = eoff[wid + 1];
    float acc[8] = {0.f, 0.f, 0.f, 0.f, 0.f, 0.f, 0.f, 0.f};
    for (int base = s; base < t; base += 64) {
        int idx_l = (base + lane < t) ? ecsr[base + lane] : 0;
        int cnt = t - base; if (cnt > 64) cnt = 64;
        int steps = (cnt + 7) >> 3;
        for (int j = 0; j < steps; j++) {
            int p = 8 * j + group;
            int mi = __shfl(idx_l, p, 64);
            if (p < cnt) {
                uint2 v = xh[(size_t)mi * 8 + gl];
                v2f d0 = __builtin_amdgcn_cvt_pk_f32_fp8(v.x, false);
                v2f d1 = __builtin_amdgcn_cvt_pk_f32_fp8(v.x, true);
                v2f d2 = __builtin_amdgcn_cvt_pk_f32_fp8(v.y, false);
                v2f d3 = __builtin_amdgcn_cvt_pk_f32_fp8(v.y, true);
                acc[0] += d0.x; acc[1] += d0.y; acc[2] += d1.x; acc[3] += d1.y;
                acc[4] += d2.x; acc[5] += d2.y; acc[6] += d3.x; acc[7] += d3.y;
            }
        }
    }
    for (int off = 8; off < 64; off <<= 1)
#pragma unroll
        for (int i = 0; i < 8; i++) acc[i] += __shfl_xor(acc[i], off, 64);
    if (group == 0) {
        int card = t - s;
        float ber = (card > 0) ? (1.0f / (float)card) : 0.f;
        uint2 o;
        o.x = enc_fp8x4(acc[0] * ber, acc[1] * ber, acc[2] * ber, acc[3] * ber);
        o.y = enc_fp8x4(acc[4] * ber, acc[5] * ber, acc[6] * ber, acc[7] * ber);
        ef[(size_t)wid * 8 + gl] = o;
    }
}

// Stage 2: one wave per node; fp8 ef gathers (8B/lane), fp32 residual + output.
// ncsr is u16 (edge ids).
__global__ void stage2_kernel(const int* __restrict__ noff, const unsigned short* __restrict__ ncsr,
                              const uint2* __restrict__ ef, const float* __restrict__ ew,
                              const float* __restrict__ x, float* __restrict__ out) {
    int wid = (blockIdx.x * 256 + threadIdx.x) >> 6;
    if (wid >= N_NODES) return;
    int lane = threadIdx.x & 63;
    int group = lane >> 3;
    int gl = lane & 7;
    int s = noff[wid], t = noff[wid + 1];
    float acc[8] = {0.f, 0.f, 0.f, 0.f, 0.f, 0.f, 0.f, 0.f};
    float dn = 0.f;
    for (int base = s; base < t; base += 64) {
        bool lv = (base + lane < t);
        int idx_l = lv ? (int)ncsr[base + lane] : 0;
        if (lv) dn += ew[idx_l];
        int cnt = t - base; if (cnt > 64) cnt = 64;
        int steps = (cnt + 7) >> 3;
        for (int j = 0; j < steps; j++) {
            int p = 8 * j + group;
            int mi = __shfl(idx_l, p, 64);
            if (p < cnt) {
                uint2 v = ef[(size_t)mi * 8 + gl];
                v2f d0 = __builtin_amdgcn_cvt_pk_f32_fp8(v.x, false);
                v2f d1 = __builtin_amdgcn_cvt_pk_f32_fp8(v.x, true);
                v2f d2 = __builtin_amdgcn_cvt_pk_f32_fp8(v.y, false);
                v2f d3 = __builtin_amdgcn_cvt_pk_f32_fp8(v.y, true);
                acc[0] += d0.x; acc[1] += d0.y; acc[2] += d1.x; acc[3] += d1.y;
                acc[4] += d2.x; acc[5] += d2.y; acc[6] += d3.x; acc[7] += d3.y;
            }
        }
    }
    for (int off = 1; off < 64; off <<= 1) dn += __shfl_xor(dn, off, 64);
    for (int off = 8; off < 64; off <<= 1)
#pragma unroll
        for (int i = 0; i < 8; i++) acc[i] += __shfl_xor(acc[i], off, 64);
    if (group == 0) {
        float dnr = (dn > 0.f) ? (1.0f / dn) : 0.f;
        const float4* x4 = (const float4*)x;
        float4* o4 = (float4*)out;
        float4 a = x4[(size_t)wid * 16 + gl * 2];
        float4 b = x4[(size_t)wid * 16 + gl * 2 + 1];
        float4 ra, rb2;
        ra.x = 0.5f * (a.x + dnr * acc[0]);
        ra.y = 0.5f * (a.y + dnr * acc[1]);
        ra.z = 0.5f * (a.z + dnr * acc[2]);
        ra.w = 0.5f * (a.w + dnr * acc[3]);
        rb2.x = 0.5f * (b.x + dnr * acc[4]);
        rb2.y = 0.5f * (b.y + dnr * acc[5]);
        rb2.z = 0.5f * (b.z + dnr * acc[6]);
        rb2.w = 0.5f * (b.w + dnr * acc[7]);
        o4[(size_t)wid * 16 + gl * 2] = ra;
        o4[(size_t)wid * 16 + gl * 2 + 1] = rb2;
    }
}

extern "C" void kernel_launch(void* const* d_in, const int* in_sizes, int n_in,
                              void* d_out, int out_size, void* d_ws, size_t ws_size,
                              hipStream_t stream) {
    const float* x        = (const float*)d_in[0];
    const int*   node_idx = (const int*)d_in[1];
    const int*   edge_idx = (const int*)d_in[2];
    const float* ew       = (const float*)d_in[3];
    float* out = (float*)d_out;

    char* ws = (char*)d_ws;
    unsigned char*  rank_n   = (unsigned char*)(ws + 0);         // 1.6MB
    unsigned char*  rank_e   = (unsigned char*)(ws + 1600000);   // 1.6MB
    int*            noff     = (int*)(ws + 3200000);             // 400004B
    int*            eoff     = (int*)(ws + 3600016);             // 200004B
    int*            cur      = (int*)(ws + 3800032);             // 256 int
    int*            pn       = (int*)(ws + 3801056);             // scan scratch
    int*            pe       = pn + 32;
    int*            bn       = pn + 64;
    int*            be       = pn + 96;
    unsigned short* node_csr = (unsigned short*)(ws + 3801600);  // 3.2MB (u16)
    int*            edge_csr = (int*)(ws + 7001600);             // 6.4MB
    unsigned short* rb       = (unsigned short*)(ws + 13401600); // 9.6MB; dead after binA
    unsigned int*   bin_n    = (unsigned int*)(ws + 23001600);   // 6.4MB
    unsigned int*   bin_e    = (unsigned int*)(ws + 29401600);   // 6.4MB
    // lifetime-overlapped scratch:
    unsigned short* cnt_g = (unsigned short*)(ws + 23001600);    // 9.6MB over bins; dead after replprefix
    int*            tot   = (int*)(ws + 3801600);                // 600KB over csr; dead after scan_write
    uint2*          ef    = (uint2*)(ws + 0);                    // fp8, written post-binA (3.2MB)
    uint2*          xh    = (uint2*)(ws + 13401600);             // fp8 over rb, written by cvt (6.4MB)

    count_kernel<<<(PN + PE) * SUBR, 1024, 0, stream>>>(node_idx, edge_idx, rank_n, rank_e, cnt_g);
    replprefix_kernel<<<(N_KEYS + 255) / 256, 256, 0, stream>>>(cnt_g, rb, tot);
    scan_partial_kernel<<<N_TILES_N + N_TILES_E, 1024, 0, stream>>>(tot, pn, pe);
    scan_base_kernel<<<1, 256, 0, stream>>>(pn, pe, bn, be, noff, eoff, cur);
    scan_write_kernel<<<N_TILES_N + N_TILES_E, 1024, 0, stream>>>(tot, bn, be, noff, eoff);
    binA_kernel<<<(M_INC / 4 + 1023) / 1024, 512, 0, stream>>>(node_idx, edge_idx, rank_n, rank_e,
                                                               rb, noff, eoff, cur, bin_n, bin_e);
    binB_kernel<<<2 * NBKT, 512, 0, stream>>>(bin_n, bin_e, node_csr, edge_csr);
    cvt_kernel<<<((N_NODES * D_HID / 8) + 255) / 256, 256, 0, stream>>>(x, xh);
    stage1_kernel<<<(N_EDGES * 64 + 255) / 256, 256, 0, stream>>>(eoff, edge_csr, xh, ef);
    stage2_kernel<<<(N_NODES * 64 + 255) / 256, 256, 0, stream>>>(noff, node_csr, ef, ew, x, out);
}

// Round 6
// 248.439 us; speedup vs baseline: 1.0732x; 1.0732x over previous
//
#include <hip/hip_runtime.h>

#define N_NODES 100000
#define N_EDGES 50000
#define N_KEYS  150000   // node keys [0,100000) then edge keys [100000,150000)
#define M_INC   1600000
#define D_HID   64

#define SUBR    32       // incidence subranges
#define SUBLEN  50000    // M_INC / SUBR
#define KPART   65536    // keys per LDS partition (u8 counts packed in 64KB LDS)
#define PN      2        // ceil(100000/65536)
#define PE      1        // ceil(50000/65536)

#define N_TILES_N 25   // ceil(100000/4096)
#define N_TILES_E 13   // ceil(50000/4096)

typedef float v2f __attribute__((ext_vector_type(2)));

// ---- workspace layout (byte offsets, lifetime-overlapped) ----
// rank_n u8 @0 (1.6MB), rank_e u8 @1600000 (1.6MB) -- dead after fill
//   ef fp8 [3.2MB] @0 overlays ranks              -- written by stage1 (post-fill)
// noff @3200000 (400004B), eoff @3600016 (200004B)
// node_csr u16 @3800032 (3.2MB), edge_csr i32 @7000032 (6.4MB) -> end 13400032
//   cnt_g u8 [32*150K=4.8MB] overlaps csr @3800032 (dead after replprefix)
// rb u8 @13400032 (4.8MB)                          -- dead after fill
//   xh fp8 [6.4MB] @13400032 overlays rb           -- written by cvt AFTER fill
// scan scratch @19800032, tot @19804128 (600KB)
// peak ~20.5 MiB

__device__ __forceinline__ unsigned enc_fp8x4(float a, float b, float c, float d) {
    unsigned r = 0;
    r = __builtin_amdgcn_cvt_pk_fp8_f32(a, b, r, false);
    r = __builtin_amdgcn_cvt_pk_fp8_f32(c, d, r, true);
    return r;
}

// Counting without global atomics: block (p,s) filters subrange s for keys in
// partition p. u8 counts packed 4-per-u32 in LDS (64KB = 65536 keys) -> only
// PN=2 node + PE=1 edge partitions. rank = old byte from packed atomicAdd.
// cnt_g stored u8 (per-subrange per-key count <= ~10).
__global__ __launch_bounds__(1024) void count_kernel(
        const int* __restrict__ node_idx, const int* __restrict__ edge_idx,
        unsigned char* __restrict__ rank_n, unsigned char* __restrict__ rank_e,
        unsigned char* __restrict__ cnt_g) {
    __shared__ unsigned int h[KPART / 4];
    int bid = blockIdx.x;
    const int* idx; unsigned char* rk; int p, s, klim, goff;
    if (bid < PN * SUBR) {
        p = bid / SUBR; s = bid % SUBR;
        idx = node_idx; rk = rank_n; klim = N_NODES; goff = 0;
    } else {
        int b2 = bid - PN * SUBR;
        p = b2 / SUBR; s = b2 % SUBR;
        idx = edge_idx; rk = rank_e; klim = N_EDGES; goff = N_NODES;
    }
    int kbase = p * KPART;
    int t = threadIdx.x;
    for (int i = t; i < KPART / 4; i += 1024) h[i] = 0;
    __syncthreads();
    int mbase = s * SUBLEN;
    const int4* src4 = (const int4*)(idx + mbase);
    for (int i = t; i < SUBLEN / 4; i += 1024) {
        int4 v = src4[i];
        int m0 = mbase + i * 4;
        int k;
        k = v.x - kbase;
        if ((unsigned)k < KPART) {
            unsigned sh = 8u * (k & 3);
            unsigned old = atomicAdd(&h[k >> 2], 1u << sh);
            rk[m0 + 0] = (unsigned char)(old >> sh);
        }
        k = v.y - kbase;
        if ((unsigned)k < KPART) {
            unsigned sh = 8u * (k & 3);
            unsigned old = atomicAdd(&h[k >> 2], 1u << sh);
            rk[m0 + 1] = (unsigned char)(old >> sh);
        }
        k = v.z - kbase;
        if ((unsigned)k < KPART) {
            unsigned sh = 8u * (k & 3);
            unsigned old = atomicAdd(&h[k >> 2], 1u << sh);
            rk[m0 + 2] = (unsigned char)(old >> sh);
        }
        k = v.w - kbase;
        if ((unsigned)k < KPART) {
            unsigned sh = 8u * (k & 3);
            unsigned old = atomicAdd(&h[k >> 2], 1u << sh);
            rk[m0 + 3] = (unsigned char)(old >> sh);
        }
    }
    __syncthreads();
    for (int i = t; i < KPART; i += 1024) {
        int key = kbase + i;
        if (key < klim)
            cnt_g[s * N_KEYS + goff + key] =
                (unsigned char)((h[i >> 2] >> (8u * (i & 3))) & 0xFFu);
    }
}

// Per-key prefix over the 32 subrange counts -> rb[s][key] (u8; prefix <= deg
// <= ~80 << 255); totals -> tot[key].
__global__ void replprefix_kernel(const unsigned char* __restrict__ cnt_g,
                                  unsigned char* __restrict__ rb, int* __restrict__ tot) {
    int key = blockIdx.x * 256 + threadIdx.x;
    if (key < N_KEYS) {
        int base = 0;
#pragma unroll
        for (int k = 0; k < SUBR; k++) {
            rb[k * N_KEYS + key] = (unsigned char)base;
            base += (int)cnt_g[k * N_KEYS + key];
        }
        tot[key] = base;
    }
}

// Scan stage 1: per-tile (4096 elements) sums over the contiguous totals array.
__global__ void scan_partial_kernel(const int* __restrict__ cnt,
                                    int* __restrict__ pn, int* __restrict__ pe) {
    __shared__ int lds[16];
    int b = blockIdx.x;
    const int* src; int nElem; int tile; int* dst;
    if (b < N_TILES_N) { src = cnt;            nElem = N_NODES; tile = b;             dst = pn; }
    else               { src = cnt + N_NODES;  nElem = N_EDGES; tile = b - N_TILES_N; dst = pe; }
    int t = threadIdx.x;
    int i4 = tile * 1024 + t;
    int sum = 0;
    if (i4 * 4 < nElem) {
        int4 v = ((const int4*)src)[i4];
        sum = v.x + v.y + v.z + v.w;
    }
    for (int off = 1; off < 64; off <<= 1) sum += __shfl_xor(sum, off, 64);
    if ((t & 63) == 0) lds[t >> 6] = sum;
    __syncthreads();
    if (t < 16) {
        int s = lds[t];
        for (int off = 1; off < 16; off <<= 1) s += __shfl_xor(s, off, 64);
        if (t == 0) dst[tile] = s;
    }
}

// Scan stage 2: exclusive scan of tile sums; writes sentinel offsets.
__global__ void scan_base_kernel(const int* __restrict__ pn, const int* __restrict__ pe,
                                 int* __restrict__ bn, int* __restrict__ be,
                                 int* __restrict__ noff, int* __restrict__ eoff) {
    int w = threadIdx.x >> 6;
    int lane = threadIdx.x & 63;
    if (w == 0) {
        int v = (lane < N_TILES_N) ? pn[lane] : 0;
        int incl = v;
        for (int d = 1; d < 64; d <<= 1) { int u = __shfl_up(incl, d, 64); if (lane >= d) incl += u; }
        if (lane < N_TILES_N) bn[lane] = incl - v;
        if (lane == N_TILES_N - 1) noff[N_NODES] = incl;
    } else {
        int v = (lane < N_TILES_E) ? pe[lane] : 0;
        int incl = v;
        for (int d = 1; d < 64; d <<= 1) { int u = __shfl_up(incl, d, 64); if (lane >= d) incl += u; }
        if (lane < N_TILES_E) be[lane] = incl - v;
        if (lane == N_TILES_E - 1) eoff[N_EDGES] = incl;
    }
}

// Scan stage 3: block-level exclusive scan of each tile + tile base, int4 I/O.
__global__ void scan_write_kernel(const int* __restrict__ cnt,
                                  const int* __restrict__ bn, const int* __restrict__ be,
                                  int* __restrict__ noff, int* __restrict__ eoff) {
    __shared__ int wsum[16];
    int b = blockIdx.x;
    const int* src; int* dst; int nElem; int tile; int tbase;
    if (b < N_TILES_N) { src = cnt;           dst = noff; nElem = N_NODES; tile = b;             tbase = bn[tile]; }
    else               { src = cnt + N_NODES; dst = eoff; nElem = N_EDGES; tile = b - N_TILES_N; tbase = be[tile]; }
    int t = threadIdx.x;
    int lane = t & 63, w = t >> 6;
    int i4 = tile * 1024 + t;
    int4 c = make_int4(0, 0, 0, 0);
    bool valid = (i4 * 4 < nElem);
    if (valid) c = ((const int4*)src)[i4];
    int tsum = c.x + c.y + c.z + c.w;
    int incl = tsum;
    for (int d = 1; d < 64; d <<= 1) { int u = __shfl_up(incl, d, 64); if (lane >= d) incl += u; }
    if (lane == 63) wsum[w] = incl;
    __syncthreads();
    if (t < 16) {
        int v = wsum[t];
        int wi = v;
        for (int d = 1; d < 16; d <<= 1) { int u = __shfl_up(wi, d, 64); if (t >= d) wi += u; }
        wsum[t] = wi - v;
    }
    __syncthreads();
    int ex = tbase + wsum[w] + incl - tsum;
    if (valid) {
        int4 o;
        o.x = ex; o.y = ex + c.x; o.z = o.y + c.y; o.w = o.z + c.z;
        ((int4*)dst)[i4] = o;
    }
}

// Fill: atomic-free scatter, 4 incidences/thread with int4/uchar4 loads.
// One-pass (r4 structure — measured best; two-pass binning was a wash, r5).
// u8 rb halves the dominant cross-XCD-refetched gather table (r5 PMC).
// node_csr u16 (edge ids < 50000). Batches never straddle subranges.
__global__ void fill_kernel(const int* __restrict__ node_idx,
                            const int* __restrict__ edge_idx,
                            const unsigned char* __restrict__ rank_n,
                            const unsigned char* __restrict__ rank_e,
                            const unsigned char* __restrict__ rb,
                            const int* __restrict__ noff, const int* __restrict__ eoff,
                            unsigned short* __restrict__ node_csr, int* __restrict__ edge_csr) {
    int q = blockIdx.x * 256 + threadIdx.x;      // batch of 4 incidences
    if (q < M_INC / 4) {
        int m0 = q * 4;
        int s = m0 / SUBLEN;
        const unsigned char* rbs = rb + s * N_KEYS;
        int4 nv = ((const int4*)node_idx)[q];
        int4 ev = ((const int4*)edge_idx)[q];
        uchar4 rn = ((const uchar4*)rank_n)[q];
        uchar4 re = ((const uchar4*)rank_e)[q];
        node_csr[noff[nv.x] + (int)rbs[nv.x] + (int)rn.x] = (unsigned short)ev.x;
        node_csr[noff[nv.y] + (int)rbs[nv.y] + (int)rn.y] = (unsigned short)ev.y;
        node_csr[noff[nv.z] + (int)rbs[nv.z] + (int)rn.z] = (unsigned short)ev.z;
        node_csr[noff[nv.w] + (int)rbs[nv.w] + (int)rn.w] = (unsigned short)ev.w;
        edge_csr[eoff[ev.x] + (int)rbs[N_NODES + ev.x] + (int)re.x] = nv.x;
        edge_csr[eoff[ev.y] + (int)rbs[N_NODES + ev.y] + (int)re.y] = nv.y;
        edge_csr[eoff[ev.z] + (int)rbs[N_NODES + ev.z] + (int)re.z] = nv.z;
        edge_csr[eoff[ev.w] + (int)rbs[N_NODES + ev.w] + (int)re.w] = nv.w;
    }
}

// Convert x (fp32) -> xh (fp8 e4m3, HW RNE). 8 elements / thread, coalesced.
__global__ void cvt_kernel(const float* __restrict__ x, uint2* __restrict__ xh) {
    int i = blockIdx.x * 256 + threadIdx.x;           // 8-element group
    if (i < (N_NODES * D_HID) / 8) {
        const float4* x4 = (const float4*)x;
        float4 a = x4[i * 2], b = x4[i * 2 + 1];
        uint2 o;
        o.x = enc_fp8x4(a.x, a.y, a.z, a.w);
        o.y = enc_fp8x4(b.x, b.y, b.z, b.w);
        xh[i] = o;
    }
}

// Stage 1: one wave per edge; 8 member-groups x 8 lanes, 8B (8 fp8) per lane.
// Output ef in fp8 (row = 64B, ef total 3.2MB).
__global__ void stage1_kernel(const int* __restrict__ eoff, const int* __restrict__ ecsr,
                              const uint2* __restrict__ xh, uint2* __restrict__ ef) {
    int wid = (blockIdx.x * 256 + threadIdx.x) >> 6;
    if (wid >= N_EDGES) return;
    int lane = threadIdx.x & 63;
    int group = lane >> 3;
    int gl = lane & 7;
    int s = eoff[wid], t = eoff[wid + 1];
    float acc[8] = {0.f, 0.f, 0.f, 0.f, 0.f, 0.f, 0.f, 0.f};
    for (int base = s; base < t; base += 64) {
        int idx_l = (base + lane < t) ? ecsr[base + lane] : 0;
        int cnt = t - base; if (cnt > 64) cnt = 64;
        int steps = (cnt + 7) >> 3;
        for (int j = 0; j < steps; j++) {
            int p = 8 * j + group;
            int mi = __shfl(idx_l, p, 64);
            if (p < cnt) {
                uint2 v = xh[(size_t)mi * 8 + gl];
                v2f d0 = __builtin_amdgcn_cvt_pk_f32_fp8(v.x, false);
                v2f d1 = __builtin_amdgcn_cvt_pk_f32_fp8(v.x, true);
                v2f d2 = __builtin_amdgcn_cvt_pk_f32_fp8(v.y, false);
                v2f d3 = __builtin_amdgcn_cvt_pk_f32_fp8(v.y, true);
                acc[0] += d0.x; acc[1] += d0.y; acc[2] += d1.x; acc[3] += d1.y;
                acc[4] += d2.x; acc[5] += d2.y; acc[6] += d3.x; acc[7] += d3.y;
            }
        }
    }
    for (int off = 8; off < 64; off <<= 1)
#pragma unroll
        for (int i = 0; i < 8; i++) acc[i] += __shfl_xor(acc[i], off, 64);
    if (group == 0) {
        int card = t - s;
        float ber = (card > 0) ? (1.0f / (float)card) : 0.f;
        uint2 o;
        o.x = enc_fp8x4(acc[0] * ber, acc[1] * ber, acc[2] * ber, acc[3] * ber);
        o.y = enc_fp8x4(acc[4] * ber, acc[5] * ber, acc[6] * ber, acc[7] * ber);
        ef[(size_t)wid * 8 + gl] = o;
    }
}

// Stage 2: one wave per node; fp8 ef gathers (8B/lane), fp32 residual + output.
// ncsr is u16 (edge ids).
__global__ void stage2_kernel(const int* __restrict__ noff, const unsigned short* __restrict__ ncsr,
                              const uint2* __restrict__ ef, const float* __restrict__ ew,
                              const float* __restrict__ x, float* __restrict__ out) {
    int wid = (blockIdx.x * 256 + threadIdx.x) >> 6;
    if (wid >= N_NODES) return;
    int lane = threadIdx.x & 63;
    int group = lane >> 3;
    int gl = lane & 7;
    int s = noff[wid], t = noff[wid + 1];
    float acc[8] = {0.f, 0.f, 0.f, 0.f, 0.f, 0.f, 0.f, 0.f};
    float dn = 0.f;
    for (int base = s; base < t; base += 64) {
        bool lv = (base + lane < t);
        int idx_l = lv ? (int)ncsr[base + lane] : 0;
        if (lv) dn += ew[idx_l];
        int cnt = t - base; if (cnt > 64) cnt = 64;
        int steps = (cnt + 7) >> 3;
        for (int j = 0; j < steps; j++) {
            int p = 8 * j + group;
            int mi = __shfl(idx_l, p, 64);
            if (p < cnt) {
                uint2 v = ef[(size_t)mi * 8 + gl];
                v2f d0 = __builtin_amdgcn_cvt_pk_f32_fp8(v.x, false);
                v2f d1 = __builtin_amdgcn_cvt_pk_f32_fp8(v.x, true);
                v2f d2 = __builtin_amdgcn_cvt_pk_f32_fp8(v.y, false);
                v2f d3 = __builtin_amdgcn_cvt_pk_f32_fp8(v.y, true);
                acc[0] += d0.x; acc[1] += d0.y; acc[2] += d1.x; acc[3] += d1.y;
                acc[4] += d2.x; acc[5] += d2.y; acc[6] += d3.x; acc[7] += d3.y;
            }
        }
    }
    for (int off = 1; off < 64; off <<= 1) dn += __shfl_xor(dn, off, 64);
    for (int off = 8; off < 64; off <<= 1)
#pragma unroll
        for (int i = 0; i < 8; i++) acc[i] += __shfl_xor(acc[i], off, 64);
    if (group == 0) {
        float dnr = (dn > 0.f) ? (1.0f / dn) : 0.f;
        const float4* x4 = (const float4*)x;
        float4* o4 = (float4*)out;
        float4 a = x4[(size_t)wid * 16 + gl * 2];
        float4 b = x4[(size_t)wid * 16 + gl * 2 + 1];
        float4 ra, rb2;
        ra.x = 0.5f * (a.x + dnr * acc[0]);
        ra.y = 0.5f * (a.y + dnr * acc[1]);
        ra.z = 0.5f * (a.z + dnr * acc[2]);
        ra.w = 0.5f * (a.w + dnr * acc[3]);
        rb2.x = 0.5f * (b.x + dnr * acc[4]);
        rb2.y = 0.5f * (b.y + dnr * acc[5]);
        rb2.z = 0.5f * (b.z + dnr * acc[6]);
        rb2.w = 0.5f * (b.w + dnr * acc[7]);
        o4[(size_t)wid * 16 + gl * 2] = ra;
        o4[(size_t)wid * 16 + gl * 2 + 1] = rb2;
    }
}

extern "C" void kernel_launch(void* const* d_in, const int* in_sizes, int n_in,
                              void* d_out, int out_size, void* d_ws, size_t ws_size,
                              hipStream_t stream) {
    const float* x        = (const float*)d_in[0];
    const int*   node_idx = (const int*)d_in[1];
    const int*   edge_idx = (const int*)d_in[2];
    const float* ew       = (const float*)d_in[3];
    float* out = (float*)d_out;

    char* ws = (char*)d_ws;
    unsigned char*  rank_n   = (unsigned char*)(ws + 0);         // 1.6MB
    unsigned char*  rank_e   = (unsigned char*)(ws + 1600000);   // 1.6MB
    int*            noff     = (int*)(ws + 3200000);             // 400004B
    int*            eoff     = (int*)(ws + 3600016);             // 200004B
    unsigned short* node_csr = (unsigned short*)(ws + 3800032);  // 3.2MB (u16)
    int*            edge_csr = (int*)(ws + 7000032);             // 6.4MB
    unsigned char*  rb       = (unsigned char*)(ws + 13400032);  // 4.8MB (u8); dead after fill
    // lifetime-overlapped scratch:
    unsigned char*  cnt_g = (unsigned char*)(ws + 3800032);      // 4.8MB under csr; dead after replprefix
    int*            pn    = (int*)(ws + 19800032);               // scan scratch; dead after scan_write
    int*            pe    = pn + 32;
    int*            bn    = pn + 64;
    int*            be    = pn + 96;
    int*            tot   = (int*)(ws + 19804128);               // 600KB; dead after scan_write
    uint2*          ef    = (uint2*)(ws + 0);                    // fp8 over ranks, post-fill (3.2MB)
    uint2*          xh    = (uint2*)(ws + 13400032);             // fp8 over rb, written by cvt (6.4MB)

    count_kernel<<<(PN + PE) * SUBR, 1024, 0, stream>>>(node_idx, edge_idx, rank_n, rank_e, cnt_g);
    replprefix_kernel<<<(N_KEYS + 255) / 256, 256, 0, stream>>>(cnt_g, rb, tot);
    scan_partial_kernel<<<N_TILES_N + N_TILES_E, 1024, 0, stream>>>(tot, pn, pe);
    scan_base_kernel<<<1, 128, 0, stream>>>(pn, pe, bn, be, noff, eoff);
    scan_write_kernel<<<N_TILES_N + N_TILES_E, 1024, 0, stream>>>(tot, bn, be, noff, eoff);
    fill_kernel<<<(M_INC / 4 + 255) / 256, 256, 0, stream>>>(node_idx, edge_idx, rank_n, rank_e,
                                                             rb, noff, eoff, node_csr, edge_csr);
    cvt_kernel<<<((N_NODES * D_HID / 8) + 255) / 256, 256, 0, stream>>>(x, xh);
    stage1_kernel<<<(N_EDGES * 64 + 255) / 256, 256, 0, stream>>>(eoff, edge_csr, xh, ef);
    stage2_kernel<<<(N_NODES * 64 + 255) / 256, 256, 0, stream>>>(noff, node_csr, ef, ew, x, out);
}

// Round 7
// 244.547 us; speedup vs baseline: 1.0903x; 1.0159x over previous
//
#include <hip/hip_runtime.h>

#define N_NODES 100000
#define N_EDGES 50000
#define N_KEYS  150000   // node keys [0,100000) then edge keys [100000,150000)
#define M_INC   1600000
#define D_HID   64

#define SUBR    32       // incidence subranges
#define SUBLEN  50000    // M_INC / SUBR
#define KPART   65536    // keys per LDS partition (u8 counts packed in 64KB LDS)
#define PN      2        // ceil(100000/65536)
#define PE      1        // ceil(50000/65536)

#define N_TILES_N 25   // ceil(100000/4096)
#define N_TILES_E 13   // ceil(50000/4096)

#define FILL_CHUNKS 49   // ceil((SUBLEN/4)/256) chunks per subrange

typedef float v2f __attribute__((ext_vector_type(2)));

// ---- workspace layout (byte offsets, lifetime-overlapped) ----
// rank_n u8 @0 (1.6MB), rank_e u8 @1600000 (1.6MB) -- dead after fill
//   ef fp8 [3.2MB] @0 overlays ranks              -- written by stage1 (post-fill)
// noff @3200000 (400004B), eoff @3600016 (200004B)
// node_csr u16 @3800032 (3.2MB), edge_csr i32 @7000032 (6.4MB) -> end 13400032
//   cnt_g u8 [32*150K=4.8MB] overlaps csr @3800032 (dead after replprefix)
// rb u8 @13400032 (4.8MB)                          -- dead after fill
//   xh fp8 [6.4MB] @13400032 overlays rb           -- written by cvt AFTER fill
// scan scratch @19800032, tot @19804128 (600KB)
// peak ~20.5 MiB

__device__ __forceinline__ unsigned enc_fp8x4(float a, float b, float c, float d) {
    unsigned r = 0;
    r = __builtin_amdgcn_cvt_pk_fp8_f32(a, b, r, false);
    r = __builtin_amdgcn_cvt_pk_fp8_f32(c, d, r, true);
    return r;
}

// Counting without global atomics: block (p,s) filters subrange s for keys in
// partition p. u8 counts packed 4-per-u32 in LDS (64KB = 65536 keys) -> only
// PN=2 node + PE=1 edge partitions. rank = old byte from packed atomicAdd.
// cnt_g stored u8 (per-subrange per-key count <= ~10).
__global__ __launch_bounds__(1024) void count_kernel(
        const int* __restrict__ node_idx, const int* __restrict__ edge_idx,
        unsigned char* __restrict__ rank_n, unsigned char* __restrict__ rank_e,
        unsigned char* __restrict__ cnt_g) {
    __shared__ unsigned int h[KPART / 4];
    int bid = blockIdx.x;
    const int* idx; unsigned char* rk; int p, s, klim, goff;
    if (bid < PN * SUBR) {
        p = bid / SUBR; s = bid % SUBR;
        idx = node_idx; rk = rank_n; klim = N_NODES; goff = 0;
    } else {
        int b2 = bid - PN * SUBR;
        p = b2 / SUBR; s = b2 % SUBR;
        idx = edge_idx; rk = rank_e; klim = N_EDGES; goff = N_NODES;
    }
    int kbase = p * KPART;
    int t = threadIdx.x;
    for (int i = t; i < KPART / 4; i += 1024) h[i] = 0;
    __syncthreads();
    int mbase = s * SUBLEN;
    const int4* src4 = (const int4*)(idx + mbase);
    for (int i = t; i < SUBLEN / 4; i += 1024) {
        int4 v = src4[i];
        int m0 = mbase + i * 4;
        int k;
        k = v.x - kbase;
        if ((unsigned)k < KPART) {
            unsigned sh = 8u * (k & 3);
            unsigned old = atomicAdd(&h[k >> 2], 1u << sh);
            rk[m0 + 0] = (unsigned char)(old >> sh);
        }
        k = v.y - kbase;
        if ((unsigned)k < KPART) {
            unsigned sh = 8u * (k & 3);
            unsigned old = atomicAdd(&h[k >> 2], 1u << sh);
            rk[m0 + 1] = (unsigned char)(old >> sh);
        }
        k = v.z - kbase;
        if ((unsigned)k < KPART) {
            unsigned sh = 8u * (k & 3);
            unsigned old = atomicAdd(&h[k >> 2], 1u << sh);
            rk[m0 + 2] = (unsigned char)(old >> sh);
        }
        k = v.w - kbase;
        if ((unsigned)k < KPART) {
            unsigned sh = 8u * (k & 3);
            unsigned old = atomicAdd(&h[k >> 2], 1u << sh);
            rk[m0 + 3] = (unsigned char)(old >> sh);
        }
    }
    __syncthreads();
    for (int i = t; i < KPART; i += 1024) {
        int key = kbase + i;
        if (key < klim)
            cnt_g[s * N_KEYS + goff + key] =
                (unsigned char)((h[i >> 2] >> (8u * (i & 3))) & 0xFFu);
    }
}

// Per-key prefix over the 32 subrange counts -> rb[s][key] (u8; prefix <= deg
// <= ~80 << 255); totals -> tot[key].
__global__ void replprefix_kernel(const unsigned char* __restrict__ cnt_g,
                                  unsigned char* __restrict__ rb, int* __restrict__ tot) {
    int key = blockIdx.x * 256 + threadIdx.x;
    if (key < N_KEYS) {
        int base = 0;
#pragma unroll
        for (int k = 0; k < SUBR; k++) {
            rb[k * N_KEYS + key] = (unsigned char)base;
            base += (int)cnt_g[k * N_KEYS + key];
        }
        tot[key] = base;
    }
}

// Scan stage 1: per-tile (4096 elements) sums over the contiguous totals array.
__global__ void scan_partial_kernel(const int* __restrict__ cnt,
                                    int* __restrict__ pn, int* __restrict__ pe) {
    __shared__ int lds[16];
    int b = blockIdx.x;
    const int* src; int nElem; int tile; int* dst;
    if (b < N_TILES_N) { src = cnt;            nElem = N_NODES; tile = b;             dst = pn; }
    else               { src = cnt + N_NODES;  nElem = N_EDGES; tile = b - N_TILES_N; dst = pe; }
    int t = threadIdx.x;
    int i4 = tile * 1024 + t;
    int sum = 0;
    if (i4 * 4 < nElem) {
        int4 v = ((const int4*)src)[i4];
        sum = v.x + v.y + v.z + v.w;
    }
    for (int off = 1; off < 64; off <<= 1) sum += __shfl_xor(sum, off, 64);
    if ((t & 63) == 0) lds[t >> 6] = sum;
    __syncthreads();
    if (t < 16) {
        int s = lds[t];
        for (int off = 1; off < 16; off <<= 1) s += __shfl_xor(s, off, 64);
        if (t == 0) dst[tile] = s;
    }
}

// Scan stage 2: exclusive scan of tile sums; writes sentinel offsets.
__global__ void scan_base_kernel(const int* __restrict__ pn, const int* __restrict__ pe,
                                 int* __restrict__ bn, int* __restrict__ be,
                                 int* __restrict__ noff, int* __restrict__ eoff) {
    int w = threadIdx.x >> 6;
    int lane = threadIdx.x & 63;
    if (w == 0) {
        int v = (lane < N_TILES_N) ? pn[lane] : 0;
        int incl = v;
        for (int d = 1; d < 64; d <<= 1) { int u = __shfl_up(incl, d, 64); if (lane >= d) incl += u; }
        if (lane < N_TILES_N) bn[lane] = incl - v;
        if (lane == N_TILES_N - 1) noff[N_NODES] = incl;
    } else {
        int v = (lane < N_TILES_E) ? pe[lane] : 0;
        int incl = v;
        for (int d = 1; d < 64; d <<= 1) { int u = __shfl_up(incl, d, 64); if (lane >= d) incl += u; }
        if (lane < N_TILES_E) be[lane] = incl - v;
        if (lane == N_TILES_E - 1) eoff[N_EDGES] = incl;
    }
}

// Scan stage 3: block-level exclusive scan of each tile + tile base, int4 I/O.
__global__ void scan_write_kernel(const int* __restrict__ cnt,
                                  const int* __restrict__ bn, const int* __restrict__ be,
                                  int* __restrict__ noff, int* __restrict__ eoff) {
    __shared__ int wsum[16];
    int b = blockIdx.x;
    const int* src; int* dst; int nElem; int tile; int tbase;
    if (b < N_TILES_N) { src = cnt;           dst = noff; nElem = N_NODES; tile = b;             tbase = bn[tile]; }
    else               { src = cnt + N_NODES; dst = eoff; nElem = N_EDGES; tile = b - N_TILES_N; tbase = be[tile]; }
    int t = threadIdx.x;
    int lane = t & 63, w = t >> 6;
    int i4 = tile * 1024 + t;
    int4 c = make_int4(0, 0, 0, 0);
    bool valid = (i4 * 4 < nElem);
    if (valid) c = ((const int4*)src)[i4];
    int tsum = c.x + c.y + c.z + c.w;
    int incl = tsum;
    for (int d = 1; d < 64; d <<= 1) { int u = __shfl_up(incl, d, 64); if (lane >= d) incl += u; }
    if (lane == 63) wsum[w] = incl;
    __syncthreads();
    if (t < 16) {
        int v = wsum[t];
        int wi = v;
        for (int d = 1; d < 16; d <<= 1) { int u = __shfl_up(wi, d, 64); if (t >= d) wi += u; }
        wsum[t] = wi - v;
    }
    __syncthreads();
    int ex = tbase + wsum[w] + incl - tsum;
    if (valid) {
        int4 o;
        o.x = ex; o.y = ex + c.x; o.z = o.y + c.y; o.w = o.z + c.z;
        ((int4*)dst)[i4] = o;
    }
}

// Fill: atomic-free scatter, 4 incidences/thread. Subrange->XCD affinity:
// block b (with assumed XCD = b%8 round-robin) processes only subrange
// s with s%8 == b%8, so each 150KB rb row is fetched into exactly ONE
// XCD's L2 (rb refetch ~25MB -> 4.8MB; r6 PMC showed rb gathers dominate
// fill FETCH). Correctness independent of the actual bid->XCD mapping.
// node_csr u16 (edge ids < 50000). Batches never straddle subranges.
__global__ __launch_bounds__(256) void fill_kernel(
        const int* __restrict__ node_idx, const int* __restrict__ edge_idx,
        const unsigned char* __restrict__ rank_n, const unsigned char* __restrict__ rank_e,
        const unsigned char* __restrict__ rb,
        const int* __restrict__ noff, const int* __restrict__ eoff,
        unsigned short* __restrict__ node_csr, int* __restrict__ edge_csr) {
    int b = blockIdx.x;
    int x = b & 7;                       // assumed XCD id
    int r = b >> 3;                      // 0..(4*FILL_CHUNKS-1)
    int g = r / FILL_CHUNKS;             // 0..3
    int c = r % FILL_CHUNKS;             // chunk within subrange
    int s = x + 8 * g;                   // subrange: s%8 == b%8
    int li = c * 256 + (int)threadIdx.x; // int4-batch within subrange
    if (li < SUBLEN / 4) {
        int q = s * (SUBLEN / 4) + li;
        const unsigned char* rbs = rb + s * N_KEYS;
        int4 nv = ((const int4*)node_idx)[q];
        int4 ev = ((const int4*)edge_idx)[q];
        uchar4 rn = ((const uchar4*)rank_n)[q];
        uchar4 re = ((const uchar4*)rank_e)[q];
        node_csr[noff[nv.x] + (int)rbs[nv.x] + (int)rn.x] = (unsigned short)ev.x;
        node_csr[noff[nv.y] + (int)rbs[nv.y] + (int)rn.y] = (unsigned short)ev.y;
        node_csr[noff[nv.z] + (int)rbs[nv.z] + (int)rn.z] = (unsigned short)ev.z;
        node_csr[noff[nv.w] + (int)rbs[nv.w] + (int)rn.w] = (unsigned short)ev.w;
        edge_csr[eoff[ev.x] + (int)rbs[N_NODES + ev.x] + (int)re.x] = nv.x;
        edge_csr[eoff[ev.y] + (int)rbs[N_NODES + ev.y] + (int)re.y] = nv.y;
        edge_csr[eoff[ev.z] + (int)rbs[N_NODES + ev.z] + (int)re.z] = nv.z;
        edge_csr[eoff[ev.w] + (int)rbs[N_NODES + ev.w] + (int)re.w] = nv.w;
    }
}

// Convert x (fp32) -> xh (fp8 e4m3, HW RNE). 8 elements / thread, coalesced.
__global__ void cvt_kernel(const float* __restrict__ x, uint2* __restrict__ xh) {
    int i = blockIdx.x * 256 + threadIdx.x;           // 8-element group
    if (i < (N_NODES * D_HID) / 8) {
        const float4* x4 = (const float4*)x;
        float4 a = x4[i * 2], b = x4[i * 2 + 1];
        uint2 o;
        o.x = enc_fp8x4(a.x, a.y, a.z, a.w);
        o.y = enc_fp8x4(b.x, b.y, b.z, b.w);
        xh[i] = o;
    }
}

// Stage 1: one wave per edge; 8 member-groups x 8 lanes, 8B (8 fp8) per lane.
// Output ef in fp8 (row = 64B, ef total 3.2MB).
__global__ void stage1_kernel(const int* __restrict__ eoff, const int* __restrict__ ecsr,
                              const uint2* __restrict__ xh, uint2* __restrict__ ef) {
    int wid = (blockIdx.x * 256 + threadIdx.x) >> 6;
    if (wid >= N_EDGES) return;
    int lane = threadIdx.x & 63;
    int group = lane >> 3;
    int gl = lane & 7;
    int s = eoff[wid], t = eoff[wid + 1];
    float acc[8] = {0.f, 0.f, 0.f, 0.f, 0.f, 0.f, 0.f, 0.f};
    for (int base = s; base < t; base += 64) {
        int idx_l = (base + lane < t) ? ecsr[base + lane] : 0;
        int cnt = t - base; if (cnt > 64) cnt = 64;
        int steps = (cnt + 7) >> 3;
        for (int j = 0; j < steps; j++) {
            int p = 8 * j + group;
            int mi = __shfl(idx_l, p, 64);
            if (p < cnt) {
                uint2 v = xh[(size_t)mi * 8 + gl];
                v2f d0 = __builtin_amdgcn_cvt_pk_f32_fp8(v.x, false);
                v2f d1 = __builtin_amdgcn_cvt_pk_f32_fp8(v.x, true);
                v2f d2 = __builtin_amdgcn_cvt_pk_f32_fp8(v.y, false);
                v2f d3 = __builtin_amdgcn_cvt_pk_f32_fp8(v.y, true);
                acc[0] += d0.x; acc[1] += d0.y; acc[2] += d1.x; acc[3] += d1.y;
                acc[4] += d2.x; acc[5] += d2.y; acc[6] += d3.x; acc[7] += d3.y;
            }
        }
    }
    for (int off = 8; off < 64; off <<= 1)
#pragma unroll
        for (int i = 0; i < 8; i++) acc[i] += __shfl_xor(acc[i], off, 64);
    if (group == 0) {
        int card = t - s;
        float ber = (card > 0) ? (1.0f / (float)card) : 0.f;
        uint2 o;
        o.x = enc_fp8x4(acc[0] * ber, acc[1] * ber, acc[2] * ber, acc[3] * ber);
        o.y = enc_fp8x4(acc[4] * ber, acc[5] * ber, acc[6] * ber, acc[7] * ber);
        ef[(size_t)wid * 8 + gl] = o;
    }
}

// Stage 2: one wave per node; fp8 ef gathers (8B/lane), fp32 residual + output.
// ncsr is u16 (edge ids).
__global__ void stage2_kernel(const int* __restrict__ noff, const unsigned short* __restrict__ ncsr,
                              const uint2* __restrict__ ef, const float* __restrict__ ew,
                              const float* __restrict__ x, float* __restrict__ out) {
    int wid = (blockIdx.x * 256 + threadIdx.x) >> 6;
    if (wid >= N_NODES) return;
    int lane = threadIdx.x & 63;
    int group = lane >> 3;
    int gl = lane & 7;
    int s = noff[wid], t = noff[wid + 1];
    float acc[8] = {0.f, 0.f, 0.f, 0.f, 0.f, 0.f, 0.f, 0.f};
    float dn = 0.f;
    for (int base = s; base < t; base += 64) {
        bool lv = (base + lane < t);
        int idx_l = lv ? (int)ncsr[base + lane] : 0;
        if (lv) dn += ew[idx_l];
        int cnt = t - base; if (cnt > 64) cnt = 64;
        int steps = (cnt + 7) >> 3;
        for (int j = 0; j < steps; j++) {
            int p = 8 * j + group;
            int mi = __shfl(idx_l, p, 64);
            if (p < cnt) {
                uint2 v = ef[(size_t)mi * 8 + gl];
                v2f d0 = __builtin_amdgcn_cvt_pk_f32_fp8(v.x, false);
                v2f d1 = __builtin_amdgcn_cvt_pk_f32_fp8(v.x, true);
                v2f d2 = __builtin_amdgcn_cvt_pk_f32_fp8(v.y, false);
                v2f d3 = __builtin_amdgcn_cvt_pk_f32_fp8(v.y, true);
                acc[0] += d0.x; acc[1] += d0.y; acc[2] += d1.x; acc[3] += d1.y;
                acc[4] += d2.x; acc[5] += d2.y; acc[6] += d3.x; acc[7] += d3.y;
            }
        }
    }
    for (int off = 1; off < 64; off <<= 1) dn += __shfl_xor(dn, off, 64);
    for (int off = 8; off < 64; off <<= 1)
#pragma unroll
        for (int i = 0; i < 8; i++) acc[i] += __shfl_xor(acc[i], off, 64);
    if (group == 0) {
        float dnr = (dn > 0.f) ? (1.0f / dn) : 0.f;
        const float4* x4 = (const float4*)x;
        float4* o4 = (float4*)out;
        float4 a = x4[(size_t)wid * 16 + gl * 2];
        float4 b = x4[(size_t)wid * 16 + gl * 2 + 1];
        float4 ra, rb2;
        ra.x = 0.5f * (a.x + dnr * acc[0]);
        ra.y = 0.5f * (a.y + dnr * acc[1]);
        ra.z = 0.5f * (a.z + dnr * acc[2]);
        ra.w = 0.5f * (a.w + dnr * acc[3]);
        rb2.x = 0.5f * (b.x + dnr * acc[4]);
        rb2.y = 0.5f * (b.y + dnr * acc[5]);
        rb2.z = 0.5f * (b.z + dnr * acc[6]);
        rb2.w = 0.5f * (b.w + dnr * acc[7]);
        o4[(size_t)wid * 16 + gl * 2] = ra;
        o4[(size_t)wid * 16 + gl * 2 + 1] = rb2;
    }
}

extern "C" void kernel_launch(void* const* d_in, const int* in_sizes, int n_in,
                              void* d_out, int out_size, void* d_ws, size_t ws_size,
                              hipStream_t stream) {
    const float* x        = (const float*)d_in[0];
    const int*   node_idx = (const int*)d_in[1];
    const int*   edge_idx = (const int*)d_in[2];
    const float* ew       = (const float*)d_in[3];
    float* out = (float*)d_out;

    char* ws = (char*)d_ws;
    unsigned char*  rank_n   = (unsigned char*)(ws + 0);         // 1.6MB
    unsigned char*  rank_e   = (unsigned char*)(ws + 1600000);   // 1.6MB
    int*            noff     = (int*)(ws + 3200000);             // 400004B
    int*            eoff     = (int*)(ws + 3600016);             // 200004B
    unsigned short* node_csr = (unsigned short*)(ws + 3800032);  // 3.2MB (u16)
    int*            edge_csr = (int*)(ws + 7000032);             // 6.4MB
    unsigned char*  rb       = (unsigned char*)(ws + 13400032);  // 4.8MB (u8); dead after fill
    // lifetime-overlapped scratch:
    unsigned char*  cnt_g = (unsigned char*)(ws + 3800032);      // 4.8MB under csr; dead after replprefix
    int*            pn    = (int*)(ws + 19800032);               // scan scratch; dead after scan_write
    int*            pe    = pn + 32;
    int*            bn    = pn + 64;
    int*            be    = pn + 96;
    int*            tot   = (int*)(ws + 19804128);               // 600KB; dead after scan_write
    uint2*          ef    = (uint2*)(ws + 0);                    // fp8 over ranks, post-fill (3.2MB)
    uint2*          xh    = (uint2*)(ws + 13400032);             // fp8 over rb, written by cvt (6.4MB)

    count_kernel<<<(PN + PE) * SUBR, 1024, 0, stream>>>(node_idx, edge_idx, rank_n, rank_e, cnt_g);
    replprefix_kernel<<<(N_KEYS + 255) / 256, 256, 0, stream>>>(cnt_g, rb, tot);
    scan_partial_kernel<<<N_TILES_N + N_TILES_E, 1024, 0, stream>>>(tot, pn, pe);
    scan_base_kernel<<<1, 128, 0, stream>>>(pn, pe, bn, be, noff, eoff);
    scan_write_kernel<<<N_TILES_N + N_TILES_E, 1024, 0, stream>>>(tot, bn, be, noff, eoff);
    fill_kernel<<<8 * (SUBR / 8) * FILL_CHUNKS, 256, 0, stream>>>(node_idx, edge_idx, rank_n, rank_e,
                                                                  rb, noff, eoff, node_csr, edge_csr);
    cvt_kernel<<<((N_NODES * D_HID / 8) + 255) / 256, 256, 0, stream>>>(x, xh);
    stage1_kernel<<<(N_EDGES * 64 + 255) / 256, 256, 0, stream>>>(eoff, edge_csr, xh, ef);
    stage2_kernel<<<(N_NODES * 64 + 255) / 256, 256, 0, stream>>>(noff, node_csr, ef, ew, x, out);
}

// Round 8
// 240.097 us; speedup vs baseline: 1.1105x; 1.0185x over previous
//
#include <hip/hip_runtime.h>

#define N_NODES 100000
#define N_EDGES 50000
#define N_KEYS  150000   // node keys [0,100000) then edge keys [100000,150000)
#define M_INC   1600000
#define D_HID   64

#define SUBR    32       // incidence subranges
#define SUBLEN  50000    // M_INC / SUBR
#define KPART   65536    // keys per LDS partition (u8 counts packed in 64KB LDS)
#define PN      2        // ceil(100000/65536)
#define PE      1        // ceil(50000/65536)

#define N_TILES_N 25   // ceil(100000/4096)
#define N_TILES_E 13   // ceil(50000/4096)

#define FILL_CHUNKS 49   // ceil((SUBLEN/4)/256) chunks per subrange

typedef float v2f __attribute__((ext_vector_type(2)));

// ---- workspace layout (byte offsets, lifetime-overlapped) ----
// rank_n u8 @0 (1.6MB), rank_e u8 @1600000 (1.6MB) -- dead after fill
//   ef fp8 [3.2MB] @0 overlays ranks               -- written by stage1 (post-fill)
// noff @3200000 (400004B), eoff @3600016 (200004B)
// node_csr u16 @3800032 (3.2MB), edge_csr i32 @7000032 (6.4MB) -> end 13400032
//   cnt_g u8 [32*150K=4.8MB] overlaps csr @3800032 (alive until absprefix;
//   csr written only in fill)
// abs u32 @13400032 (19.2MB)                        -- dead after fill
//   xh fp8 [6.4MB] @13400032 overlays abs           -- written by cvt AFTER fill
// tot @32600032 (600KB; dead after scan_write), scan scratch @33200032
// peak ~33.2 MiB

__device__ __forceinline__ unsigned enc_fp8x4(float a, float b, float c, float d) {
    unsigned r = 0;
    r = __builtin_amdgcn_cvt_pk_fp8_f32(a, b, r, false);
    r = __builtin_amdgcn_cvt_pk_fp8_f32(c, d, r, true);
    return r;
}

// Counting without global atomics: block (p,s) filters subrange s for keys in
// partition p. u8 counts packed 4-per-u32 in LDS (64KB = 65536 keys) -> only
// PN=2 node + PE=1 edge partitions. rank = old byte from packed atomicAdd.
// cnt_g stored u8 (per-subrange per-key count <= ~10).
__global__ __launch_bounds__(1024) void count_kernel(
        const int* __restrict__ node_idx, const int* __restrict__ edge_idx,
        unsigned char* __restrict__ rank_n, unsigned char* __restrict__ rank_e,
        unsigned char* __restrict__ cnt_g) {
    __shared__ unsigned int h[KPART / 4];
    int bid = blockIdx.x;
    const int* idx; unsigned char* rk; int p, s, klim, goff;
    if (bid < PN * SUBR) {
        p = bid / SUBR; s = bid % SUBR;
        idx = node_idx; rk = rank_n; klim = N_NODES; goff = 0;
    } else {
        int b2 = bid - PN * SUBR;
        p = b2 / SUBR; s = b2 % SUBR;
        idx = edge_idx; rk = rank_e; klim = N_EDGES; goff = N_NODES;
    }
    int kbase = p * KPART;
    int t = threadIdx.x;
    for (int i = t; i < KPART / 4; i += 1024) h[i] = 0;
    __syncthreads();
    int mbase = s * SUBLEN;
    const int4* src4 = (const int4*)(idx + mbase);
    for (int i = t; i < SUBLEN / 4; i += 1024) {
        int4 v = src4[i];
        int m0 = mbase + i * 4;
        int k;
        k = v.x - kbase;
        if ((unsigned)k < KPART) {
            unsigned sh = 8u * (k & 3);
            unsigned old = atomicAdd(&h[k >> 2], 1u << sh);
            rk[m0 + 0] = (unsigned char)(old >> sh);
        }
        k = v.y - kbase;
        if ((unsigned)k < KPART) {
            unsigned sh = 8u * (k & 3);
            unsigned old = atomicAdd(&h[k >> 2], 1u << sh);
            rk[m0 + 1] = (unsigned char)(old >> sh);
        }
        k = v.z - kbase;
        if ((unsigned)k < KPART) {
            unsigned sh = 8u * (k & 3);
            unsigned old = atomicAdd(&h[k >> 2], 1u << sh);
            rk[m0 + 2] = (unsigned char)(old >> sh);
        }
        k = v.w - kbase;
        if ((unsigned)k < KPART) {
            unsigned sh = 8u * (k & 3);
            unsigned old = atomicAdd(&h[k >> 2], 1u << sh);
            rk[m0 + 3] = (unsigned char)(old >> sh);
        }
    }
    __syncthreads();
    for (int i = t; i < KPART; i += 1024) {
        int key = kbase + i;
        if (key < klim)
            cnt_g[s * N_KEYS + goff + key] =
                (unsigned char)((h[i >> 2] >> (8u * (i & 3))) & 0xFFu);
    }
}

// Totals per key (feeds the offset scans). Replaces replprefix's sum role.
__global__ void totsum_kernel(const unsigned char* __restrict__ cnt_g,
                              int* __restrict__ tot) {
    int key = blockIdx.x * 256 + threadIdx.x;
    if (key < N_KEYS) {
        int base = 0;
#pragma unroll
        for (int k = 0; k < SUBR; k++) base += (int)cnt_g[k * N_KEYS + key];
        tot[key] = base;
    }
}

// Scan stage 1: per-tile (4096 elements) sums over the contiguous totals array.
__global__ void scan_partial_kernel(const int* __restrict__ cnt,
                                    int* __restrict__ pn, int* __restrict__ pe) {
    __shared__ int lds[16];
    int b = blockIdx.x;
    const int* src; int nElem; int tile; int* dst;
    if (b < N_TILES_N) { src = cnt;            nElem = N_NODES; tile = b;             dst = pn; }
    else               { src = cnt + N_NODES;  nElem = N_EDGES; tile = b - N_TILES_N; dst = pe; }
    int t = threadIdx.x;
    int i4 = tile * 1024 + t;
    int sum = 0;
    if (i4 * 4 < nElem) {
        int4 v = ((const int4*)src)[i4];
        sum = v.x + v.y + v.z + v.w;
    }
    for (int off = 1; off < 64; off <<= 1) sum += __shfl_xor(sum, off, 64);
    if ((t & 63) == 0) lds[t >> 6] = sum;
    __syncthreads();
    if (t < 16) {
        int s = lds[t];
        for (int off = 1; off < 16; off <<= 1) s += __shfl_xor(s, off, 64);
        if (t == 0) dst[tile] = s;
    }
}

// Scan stage 2: exclusive scan of tile sums; writes sentinel offsets.
__global__ void scan_base_kernel(const int* __restrict__ pn, const int* __restrict__ pe,
                                 int* __restrict__ bn, int* __restrict__ be,
                                 int* __restrict__ noff, int* __restrict__ eoff) {
    int w = threadIdx.x >> 6;
    int lane = threadIdx.x & 63;
    if (w == 0) {
        int v = (lane < N_TILES_N) ? pn[lane] : 0;
        int incl = v;
        for (int d = 1; d < 64; d <<= 1) { int u = __shfl_up(incl, d, 64); if (lane >= d) incl += u; }
        if (lane < N_TILES_N) bn[lane] = incl - v;
        if (lane == N_TILES_N - 1) noff[N_NODES] = incl;
    } else {
        int v = (lane < N_TILES_E) ? pe[lane] : 0;
        int incl = v;
        for (int d = 1; d < 64; d <<= 1) { int u = __shfl_up(incl, d, 64); if (lane >= d) incl += u; }
        if (lane < N_TILES_E) be[lane] = incl - v;
        if (lane == N_TILES_E - 1) eoff[N_EDGES] = incl;
    }
}

// Scan stage 3: block-level exclusive scan of each tile + tile base, int4 I/O.
__global__ void scan_write_kernel(const int* __restrict__ cnt,
                                  const int* __restrict__ bn, const int* __restrict__ be,
                                  int* __restrict__ noff, int* __restrict__ eoff) {
    __shared__ int wsum[16];
    int b = blockIdx.x;
    const int* src; int* dst; int nElem; int tile; int tbase;
    if (b < N_TILES_N) { src = cnt;           dst = noff; nElem = N_NODES; tile = b;             tbase = bn[tile]; }
    else               { src = cnt + N_NODES; dst = eoff; nElem = N_EDGES; tile = b - N_TILES_N; tbase = be[tile]; }
    int t = threadIdx.x;
    int lane = t & 63, w = t >> 6;
    int i4 = tile * 1024 + t;
    int4 c = make_int4(0, 0, 0, 0);
    bool valid = (i4 * 4 < nElem);
    if (valid) c = ((const int4*)src)[i4];
    int tsum = c.x + c.y + c.z + c.w;
    int incl = tsum;
    for (int d = 1; d < 64; d <<= 1) { int u = __shfl_up(incl, d, 64); if (lane >= d) incl += u; }
    if (lane == 63) wsum[w] = incl;
    __syncthreads();
    if (t < 16) {
        int v = wsum[t];
        int wi = v;
        for (int d = 1; d < 16; d <<= 1) { int u = __shfl_up(wi, d, 64); if (t >= d) wi += u; }
        wsum[t] = wi - v;
    }
    __syncthreads();
    int ex = tbase + wsum[w] + incl - tsum;
    if (valid) {
        int4 o;
        o.x = ex; o.y = ex + c.x; o.z = o.y + c.y; o.w = o.z + c.z;
        ((int4*)dst)[i4] = o;
    }
}

// Absolute-base table: abs[s][key] = off[key] + sum_{k<s} cnt[k][key] (u32).
// Fuses the old noff/eoff + rb pair into ONE random gather for fill
// (16 -> 8 random gathers/thread; fill is transaction-bound per r6/r7 PMC).
// Slot values are bit-identical to noff+rb+rank.
__global__ void absprefix_kernel(const unsigned char* __restrict__ cnt_g,
                                 const int* __restrict__ noff, const int* __restrict__ eoff,
                                 unsigned int* __restrict__ absb) {
    int key = blockIdx.x * 256 + threadIdx.x;
    if (key < N_KEYS) {
        unsigned base = (key < N_NODES) ? (unsigned)noff[key]
                                        : (unsigned)eoff[key - N_NODES];
#pragma unroll
        for (int k = 0; k < SUBR; k++) {
            absb[k * N_KEYS + key] = base;
            base += (unsigned)cnt_g[k * N_KEYS + key];
        }
    }
}

// Fill: atomic-free scatter, 4 incidences/thread. Subrange->XCD affinity
// (block b with assumed XCD b%8 processes only subranges s%8==b%8) keeps each
// 600KB abs row in exactly one XCD's L2 (4 rows = 2.4MB/XCD). One random
// gather (abs) + coalesced rank per incidence side. node_csr u16.
__global__ __launch_bounds__(256) void fill_kernel(
        const int* __restrict__ node_idx, const int* __restrict__ edge_idx,
        const unsigned char* __restrict__ rank_n, const unsigned char* __restrict__ rank_e,
        const unsigned int* __restrict__ absb,
        unsigned short* __restrict__ node_csr, int* __restrict__ edge_csr) {
    int b = blockIdx.x;
    int x = b & 7;                       // assumed XCD id
    int r = b >> 3;                      // 0..(4*FILL_CHUNKS-1)
    int g = r / FILL_CHUNKS;             // 0..3
    int c = r % FILL_CHUNKS;             // chunk within subrange
    int s = x + 8 * g;                   // subrange: s%8 == b%8
    int li = c * 256 + (int)threadIdx.x; // int4-batch within subrange
    if (li < SUBLEN / 4) {
        int q = s * (SUBLEN / 4) + li;
        const unsigned int* ab = absb + s * N_KEYS;
        int4 nv = ((const int4*)node_idx)[q];
        int4 ev = ((const int4*)edge_idx)[q];
        uchar4 rn = ((const uchar4*)rank_n)[q];
        uchar4 re = ((const uchar4*)rank_e)[q];
        node_csr[ab[nv.x] + (unsigned)rn.x] = (unsigned short)ev.x;
        node_csr[ab[nv.y] + (unsigned)rn.y] = (unsigned short)ev.y;
        node_csr[ab[nv.z] + (unsigned)rn.z] = (unsigned short)ev.z;
        node_csr[ab[nv.w] + (unsigned)rn.w] = (unsigned short)ev.w;
        edge_csr[ab[N_NODES + ev.x] + (unsigned)re.x] = nv.x;
        edge_csr[ab[N_NODES + ev.y] + (unsigned)re.y] = nv.y;
        edge_csr[ab[N_NODES + ev.z] + (unsigned)re.z] = nv.z;
        edge_csr[ab[N_NODES + ev.w] + (unsigned)re.w] = nv.w;
    }
}

// Convert x (fp32) -> xh (fp8 e4m3, HW RNE). 8 elements / thread, coalesced.
__global__ void cvt_kernel(const float* __restrict__ x, uint2* __restrict__ xh) {
    int i = blockIdx.x * 256 + threadIdx.x;           // 8-element group
    if (i < (N_NODES * D_HID) / 8) {
        const float4* x4 = (const float4*)x;
        float4 a = x4[i * 2], b = x4[i * 2 + 1];
        uint2 o;
        o.x = enc_fp8x4(a.x, a.y, a.z, a.w);
        o.y = enc_fp8x4(b.x, b.y, b.z, b.w);
        xh[i] = o;
    }
}

// Stage 1: one wave per edge; 8 member-groups x 8 lanes, 8B (8 fp8) per lane.
// Output ef in fp8 (row = 64B, ef total 3.2MB).
__global__ void stage1_kernel(const int* __restrict__ eoff, const int* __restrict__ ecsr,
                              const uint2* __restrict__ xh, uint2* __restrict__ ef) {
    int wid = (blockIdx.x * 256 + threadIdx.x) >> 6;
    if (wid >= N_EDGES) return;
    int lane = threadIdx.x & 63;
    int group = lane >> 3;
    int gl = lane & 7;
    int s = eoff[wid], t = eoff[wid + 1];
    float acc[8] = {0.f, 0.f, 0.f, 0.f, 0.f, 0.f, 0.f, 0.f};
    for (int base = s; base < t; base += 64) {
        int idx_l = (base + lane < t) ? ecsr[base + lane] : 0;
        int cnt = t - base; if (cnt > 64) cnt = 64;
        int steps = (cnt + 7) >> 3;
        for (int j = 0; j < steps; j++) {
            int p = 8 * j + group;
            int mi = __shfl(idx_l, p, 64);
            if (p < cnt) {
                uint2 v = xh[(size_t)mi * 8 + gl];
                v2f d0 = __builtin_amdgcn_cvt_pk_f32_fp8(v.x, false);
                v2f d1 = __builtin_amdgcn_cvt_pk_f32_fp8(v.x, true);
                v2f d2 = __builtin_amdgcn_cvt_pk_f32_fp8(v.y, false);
                v2f d3 = __builtin_amdgcn_cvt_pk_f32_fp8(v.y, true);
                acc[0] += d0.x; acc[1] += d0.y; acc[2] += d1.x; acc[3] += d1.y;
                acc[4] += d2.x; acc[5] += d2.y; acc[6] += d3.x; acc[7] += d3.y;
            }
        }
    }
    for (int off = 8; off < 64; off <<= 1)
#pragma unroll
        for (int i = 0; i < 8; i++) acc[i] += __shfl_xor(acc[i], off, 64);
    if (group == 0) {
        int card = t - s;
        float ber = (card > 0) ? (1.0f / (float)card) : 0.f;
        uint2 o;
        o.x = enc_fp8x4(acc[0] * ber, acc[1] * ber, acc[2] * ber, acc[3] * ber);
        o.y = enc_fp8x4(acc[4] * ber, acc[5] * ber, acc[6] * ber, acc[7] * ber);
        ef[(size_t)wid * 8 + gl] = o;
    }
}

// Stage 2: one wave per node; fp8 ef gathers (8B/lane), fp32 residual + output.
// ncsr is u16 (edge ids).
__global__ void stage2_kernel(const int* __restrict__ noff, const unsigned short* __restrict__ ncsr,
                              const uint2* __restrict__ ef, const float* __restrict__ ew,
                              const float* __restrict__ x, float* __restrict__ out) {
    int wid = (blockIdx.x * 256 + threadIdx.x) >> 6;
    if (wid >= N_NODES) return;
    int lane = threadIdx.x & 63;
    int group = lane >> 3;
    int gl = lane & 7;
    int s = noff[wid], t = noff[wid + 1];
    float acc[8] = {0.f, 0.f, 0.f, 0.f, 0.f, 0.f, 0.f, 0.f};
    float dn = 0.f;
    for (int base = s; base < t; base += 64) {
        bool lv = (base + lane < t);
        int idx_l = lv ? (int)ncsr[base + lane] : 0;
        if (lv) dn += ew[idx_l];
        int cnt = t - base; if (cnt > 64) cnt = 64;
        int steps = (cnt + 7) >> 3;
        for (int j = 0; j < steps; j++) {
            int p = 8 * j + group;
            int mi = __shfl(idx_l, p, 64);
            if (p < cnt) {
                uint2 v = ef[(size_t)mi * 8 + gl];
                v2f d0 = __builtin_amdgcn_cvt_pk_f32_fp8(v.x, false);
                v2f d1 = __builtin_amdgcn_cvt_pk_f32_fp8(v.x, true);
                v2f d2 = __builtin_amdgcn_cvt_pk_f32_fp8(v.y, false);
                v2f d3 = __builtin_amdgcn_cvt_pk_f32_fp8(v.y, true);
                acc[0] += d0.x; acc[1] += d0.y; acc[2] += d1.x; acc[3] += d1.y;
                acc[4] += d2.x; acc[5] += d2.y; acc[6] += d3.x; acc[7] += d3.y;
            }
        }
    }
    for (int off = 1; off < 64; off <<= 1) dn += __shfl_xor(dn, off, 64);
    for (int off = 8; off < 64; off <<= 1)
#pragma unroll
        for (int i = 0; i < 8; i++) acc[i] += __shfl_xor(acc[i], off, 64);
    if (group == 0) {
        float dnr = (dn > 0.f) ? (1.0f / dn) : 0.f;
        const float4* x4 = (const float4*)x;
        float4* o4 = (float4*)out;
        float4 a = x4[(size_t)wid * 16 + gl * 2];
        float4 b = x4[(size_t)wid * 16 + gl * 2 + 1];
        float4 ra, rb2;
        ra.x = 0.5f * (a.x + dnr * acc[0]);
        ra.y = 0.5f * (a.y + dnr * acc[1]);
        ra.z = 0.5f * (a.z + dnr * acc[2]);
        ra.w = 0.5f * (a.w + dnr * acc[3]);
        rb2.x = 0.5f * (b.x + dnr * acc[4]);
        rb2.y = 0.5f * (b.y + dnr * acc[5]);
        rb2.z = 0.5f * (b.z + dnr * acc[6]);
        rb2.w = 0.5f * (b.w + dnr * acc[7]);
        o4[(size_t)wid * 16 + gl * 2] = ra;
        o4[(size_t)wid * 16 + gl * 2 + 1] = rb2;
    }
}

extern "C" void kernel_launch(void* const* d_in, const int* in_sizes, int n_in,
                              void* d_out, int out_size, void* d_ws, size_t ws_size,
                              hipStream_t stream) {
    const float* x        = (const float*)d_in[0];
    const int*   node_idx = (const int*)d_in[1];
    const int*   edge_idx = (const int*)d_in[2];
    const float* ew       = (const float*)d_in[3];
    float* out = (float*)d_out;

    char* ws = (char*)d_ws;
    unsigned char*  rank_n   = (unsigned char*)(ws + 0);         // 1.6MB
    unsigned char*  rank_e   = (unsigned char*)(ws + 1600000);   // 1.6MB
    int*            noff     = (int*)(ws + 3200000);             // 400004B
    int*            eoff     = (int*)(ws + 3600016);             // 200004B
    unsigned short* node_csr = (unsigned short*)(ws + 3800032);  // 3.2MB (u16)
    int*            edge_csr = (int*)(ws + 7000032);             // 6.4MB
    unsigned int*   absb     = (unsigned int*)(ws + 13400032);   // 19.2MB (u32); dead after fill
    // lifetime-overlapped scratch:
    unsigned char*  cnt_g = (unsigned char*)(ws + 3800032);      // 4.8MB under csr; alive until absprefix
    int*            tot   = (int*)(ws + 32600032);               // 600KB; dead after scan_write
    int*            pn    = (int*)(ws + 33200032);               // scan scratch
    int*            pe    = pn + 32;
    int*            bn    = pn + 64;
    int*            be    = pn + 96;
    uint2*          ef    = (uint2*)(ws + 0);                    // fp8 over ranks, post-fill (3.2MB)
    uint2*          xh    = (uint2*)(ws + 13400032);             // fp8 over absb, written by cvt (6.4MB)

    count_kernel<<<(PN + PE) * SUBR, 1024, 0, stream>>>(node_idx, edge_idx, rank_n, rank_e, cnt_g);
    totsum_kernel<<<(N_KEYS + 255) / 256, 256, 0, stream>>>(cnt_g, tot);
    scan_partial_kernel<<<N_TILES_N + N_TILES_E, 1024, 0, stream>>>(tot, pn, pe);
    scan_base_kernel<<<1, 128, 0, stream>>>(pn, pe, bn, be, noff, eoff);
    scan_write_kernel<<<N_TILES_N + N_TILES_E, 1024, 0, stream>>>(tot, bn, be, noff, eoff);
    absprefix_kernel<<<(N_KEYS + 255) / 256, 256, 0, stream>>>(cnt_g, noff, eoff, absb);
    fill_kernel<<<8 * (SUBR / 8) * FILL_CHUNKS, 256, 0, stream>>>(node_idx, edge_idx, rank_n, rank_e,
                                                                  absb, node_csr, edge_csr);
    cvt_kernel<<<((N_NODES * D_HID / 8) + 255) / 256, 256, 0, stream>>>(x, xh);
    stage1_kernel<<<(N_EDGES * 64 + 255) / 256, 256, 0, stream>>>(eoff, edge_csr, xh, ef);
    stage2_kernel<<<(N_NODES * 64 + 255) / 256, 256, 0, stream>>>(noff, node_csr, ef, ew, x, out);
}